// Round 6
// baseline (197.188 us; speedup 1.0000x reference)
//
#include <hip/hip_runtime.h>
#include <stdint.h>

// CycleFC 1w1a: out[b,o,h,w] = sum_c sign(x)[b,c,h,w+off(c)] * sign(W)[o,c] + bias[o]
// off(c) = (c+3)%7 - 3, zero-pad OOB. B=64, C=O=384, H=W=32.
//
// Binary-GEMM: pack signs (bit=1 iff <0) into 6 u64 words; out = bias2 - 2*popc(G^WB).
// bias2t[w][o] = bias[o] + Nvalid(w) + 2*popc(WB & ~V(w)) precomputed in prep.
// Offsets periodic mod 7; 64%7==1 so mask for offset d in word j is Pm[(d-j) mod 7].
//
// R6: monolithic pack->barrier->GEMM plateaued at 71-91us across all variants
// (VALUBusy ~30% with 6 waves/SIMD => waves stalled ~95%: intra-block
// serialization of HBM-latency loads + barriers + dependent fetches).
// Decouple: G for the WHOLE tensor is only 3 MB (L2-resident). Kernel A
// streams x -> G (read-bound, no consumer). Kernel B is a barrier-free
// register-tiled binary GEMM at 8 blocks/CU: G in VGPRs, weights via
// wave-uniform s_loads, bias via per-chunk float4, 256B contiguous stores.

#define IN_CH 384
#define HH 32
#define WW 32
#define BB 64
#define HR 4  // h rows per pack block

constexpr uint64_t P7(int t) {
  uint64_t m = 0;
  for (int k = 0; k < 64; ++k)
    if (k % 7 == t) m |= (1ull << k);
  return m;
}
__device__ __constant__ uint64_t Pm[7] = {P7(0), P7(1), P7(2), P7(3), P7(4), P7(5), P7(6)};

// ---------------- prep: one block (1 wave) per output channel o --------------
__global__ __launch_bounds__(64) void cyc_prep(const float* __restrict__ wgt,
                                               const float* __restrict__ bias,
                                               uint64_t* __restrict__ wbg,
                                               float* __restrict__ bias2t) {
  const int o = blockIdx.x;
  const int lane = threadIdx.x;
  __shared__ uint64_t wb_sh[6];
#pragma unroll
  for (int j = 0; j < 6; ++j) {
    uint64_t m = __ballot(wgt[o * IN_CH + j * 64 + lane] < 0.0f);
    if (lane == 0) wb_sh[j] = m;
  }
  __syncthreads();
  if (lane < 6) wbg[o * 6 + lane] = wb_sh[lane];
  if (lane < WW) {
    const int w = lane;
    int nv = 0, corr = 0;
#pragma unroll
    for (int j = 0; j < 6; ++j) {
      uint64_t V = 0;
#pragma unroll
      for (int d = -3; d <= 3; ++d) {
        int wd = w + d;
        if (wd >= 0 && wd < WW) V |= Pm[(d - j + 14) % 7];
      }
      nv += __popcll(V);
      corr += __popcll(wb_sh[j] & ~V);
    }
    bias2t[w * IN_CH + o] = bias[o] + (float)nv + 2.0f * (float)corr;
  }
}

// ---------------- A: pack x signs -> shifted/masked G bits (3 MB) ------------
// block = (b, 4 h-rows), 768 threads. G[p*6+j], p = (b*32+h)*32+w.
__global__ __launch_bounds__(768) void cyc_pack(const float* __restrict__ x,
                                                uint64_t* __restrict__ G) {
  __shared__ uint64_t sh_X[HR][WW][6];  // 6144 B
  const int t = threadIdx.x;
  const int b = blockIdx.x >> 3;
  const int h0 = (blockIdx.x & 7) * HR;
  const int wave = t >> 6, lane = t & 63;

  // 24 (r,j) pack tasks over 12 waves (2 each): lane owns channel c=j*64+lane,
  // loads its 128B w-row of row h0+r, 32 ballots bit-transpose into sh_X.
#pragma unroll
  for (int p = 0; p < 2; ++p) {
    const int tau = wave + p * 12;
    const int r = tau / 6, j = tau % 6;
    const int c = j * 64 + lane;
    const float4* xp = reinterpret_cast<const float4*>(
        x + (size_t)((b * IN_CH + c) * HH + h0 + r) * WW);
    unsigned myw = 0;
#pragma unroll
    for (int i = 0; i < 8; ++i) {
      float4 v = xp[i];
      myw |= (v.x < 0.0f ? 1u : 0u) << (i * 4 + 0);
      myw |= (v.y < 0.0f ? 1u : 0u) << (i * 4 + 1);
      myw |= (v.z < 0.0f ? 1u : 0u) << (i * 4 + 2);
      myw |= (v.w < 0.0f ? 1u : 0u) << (i * 4 + 3);
    }
#pragma unroll
    for (int w = 0; w < WW; ++w) {
      uint64_t m = __ballot((myw >> w) & 1u);
      if (lane == 0) sh_X[r][w][j] = m;
    }
  }
  __syncthreads();

  // shift/mask: t = r*192 + w*6 + j (j fastest -> coalesced 6 KB store)
  const int r = t / 192, q = t % 192, w = q / 6, j = q % 6;
  uint64_t g = 0;
#pragma unroll
  for (int d = -3; d <= 3; ++d) {
    int wd = w + d;
    if (wd >= 0 && wd < WW) g |= sh_X[r][wd][j] & Pm[(d - j + 14) % 7];
  }
  G[(size_t)blockIdx.x * 768 + t] = g;
}

// ---------------- B: barrier-free binary GEMM --------------------------------
// block = 256 thr (4 waves); block = (pixel-group of 64 px) x (o-half).
// wave = that pixel-group x 48-o range. grid 2048 -> 8 blocks/CU.
__global__ __launch_bounds__(256) void cyc_gemm(const uint64_t* __restrict__ G,
                                                const uint64_t* __restrict__ wbg,
                                                const float* __restrict__ bias2t,
                                                float* __restrict__ out) {
  const int t = threadIdx.x;
  const int wv = t >> 6, lane = t & 63;
  const int pg = blockIdx.x >> 1;  // pixel-group 0..1023 (64 px each)
  const int oq = __builtin_amdgcn_readfirstlane(((blockIdx.x & 1) * 4 + wv) * 48);
  const int b = pg >> 4;            // 16 groups per image (1024 px)
  const int hw0 = (pg & 15) * 64;   // within-image pixel offset
  // my pixel's 6 G words -> 12 VGPRs (48 B/lane, 3x dwordx4, L2-resident)
  const ulonglong2* gp =
      reinterpret_cast<const ulonglong2*>(G + ((size_t)pg * 64 + lane) * 6);
  const ulonglong2 q0 = gp[0], q1 = gp[1], q2 = gp[2];
  const uint64_t g0 = q0.x, g1 = q0.y, g2 = q1.x, g3 = q1.y, g4 = q2.x, g5 = q2.y;
  const int w = lane & 31;
  float* op = out + ((size_t)b * IN_CH + oq) * (HH * WW) + hw0 + lane;
  const uint64_t* wp = wbg + oq * 6;       // wave-uniform -> s_load
  const float* bp = bias2t + w * IN_CH + oq;
#pragma unroll 1
  for (int ch = 0; ch < 12; ++ch) {  // 12 chunks x 4 o
    const float4 bb = *reinterpret_cast<const float4*>(bp + ch * 4);
    const uint64_t* wo = wp + ch * 24;
#pragma unroll
    for (int oo = 0; oo < 4; ++oo) {
      int mm = __popcll(g0 ^ wo[oo * 6 + 0]) + __popcll(g1 ^ wo[oo * 6 + 1]) +
               __popcll(g2 ^ wo[oo * 6 + 2]) + __popcll(g3 ^ wo[oo * 6 + 3]) +
               __popcll(g4 ^ wo[oo * 6 + 4]) + __popcll(g5 ^ wo[oo * 6 + 5]);
      const float bv = (oo == 0) ? bb.x : (oo == 1) ? bb.y : (oo == 2) ? bb.z : bb.w;
      op[(size_t)(ch * 4 + oo) * (HH * WW)] = bv - 2.0f * (float)mm;
    }
  }
}

// ---------------- fallback (R5 monolithic) if ws too small -------------------
__global__ __launch_bounds__(768) void cyc_main(const float* __restrict__ x,
                                                const uint64_t* __restrict__ wbg,
                                                const float* __restrict__ bias2t,
                                                float* __restrict__ out) {
  __shared__ uint64_t sh_X[HR][WW][6];
  __shared__ uint64_t sh_G[HR][WW][6];
  const int t = threadIdx.x;
  const int b = blockIdx.x >> 3;
  const int h0 = (blockIdx.x & 7) * HR;
  const int wave = t >> 6, lane = t & 63;
#pragma unroll
  for (int p = 0; p < 2; ++p) {
    const int tau = wave + p * 12;
    const int r = tau / 6, j = tau % 6;
    const int c = j * 64 + lane;
    const float4* xp = reinterpret_cast<const float4*>(
        x + (size_t)((b * IN_CH + c) * HH + h0 + r) * WW);
    unsigned myw = 0;
#pragma unroll
    for (int i = 0; i < 8; ++i) {
      float4 v = xp[i];
      myw |= (v.x < 0.0f ? 1u : 0u) << (i * 4 + 0);
      myw |= (v.y < 0.0f ? 1u : 0u) << (i * 4 + 1);
      myw |= (v.z < 0.0f ? 1u : 0u) << (i * 4 + 2);
      myw |= (v.w < 0.0f ? 1u : 0u) << (i * 4 + 3);
    }
#pragma unroll
    for (int w = 0; w < WW; ++w) {
      uint64_t m = __ballot((myw >> w) & 1u);
      if (lane == 0) sh_X[r][w][j] = m;
    }
  }
  __syncthreads();
  {
    const int r = t / (WW * 6);
    const int q = t % (WW * 6);
    const int w = q & 31, j = q >> 5;
    uint64_t g = 0;
#pragma unroll
    for (int d = -3; d <= 3; ++d) {
      int wd = w + d;
      if (wd >= 0 && wd < WW) g |= sh_X[r][wd][j] & Pm[(d - j + 14) % 7];
    }
    sh_G[r][w][j] = g;
  }
  __syncthreads();
  const int og = __builtin_amdgcn_readfirstlane(wave);
  const int w = lane & 31, r2 = lane >> 5;
  uint64_t gA[6], gB[6];
  {
    const ulonglong2* gv = reinterpret_cast<const ulonglong2*>(&sh_G[r2][w][0]);
    ulonglong2 a0 = gv[0], a1 = gv[1], a2 = gv[2];
    gA[0] = a0.x; gA[1] = a0.y; gA[2] = a1.x; gA[3] = a1.y; gA[4] = a2.x; gA[5] = a2.y;
    const ulonglong2* hv = reinterpret_cast<const ulonglong2*>(&sh_G[2 + r2][w][0]);
    ulonglong2 b0 = hv[0], b1 = hv[1], b2 = hv[2];
    gB[0] = b0.x; gB[1] = b0.y; gB[2] = b1.x; gB[3] = b1.y; gB[4] = b2.x; gB[5] = b2.y;
  }
  float bbv[32];
  {
    const float4* bsrc = reinterpret_cast<const float4*>(bias2t + w * IN_CH);
    float4* bdst = reinterpret_cast<float4*>(bbv);
#pragma unroll
    for (int i = 0; i < 8; ++i) bdst[i] = bsrc[(og * 32) / 4 + i];
  }
  float* opA = out + ((size_t)b * IN_CH + og * 32) * (HH * WW) + h0 * WW + lane;
  float* opB = opA + 2 * WW;
  const uint64_t* wp = wbg + og * 32 * 6;
#pragma unroll
  for (int i = 0; i < 32; ++i) {
    const uint64_t w0 = wp[i * 6 + 0], w1 = wp[i * 6 + 1], w2 = wp[i * 6 + 2];
    const uint64_t w3 = wp[i * 6 + 3], w4 = wp[i * 6 + 4], w5 = wp[i * 6 + 5];
    int mmA = __popcll(gA[0] ^ w0) + __popcll(gA[1] ^ w1) + __popcll(gA[2] ^ w2) +
              __popcll(gA[3] ^ w3) + __popcll(gA[4] ^ w4) + __popcll(gA[5] ^ w5);
    int mmB = __popcll(gB[0] ^ w0) + __popcll(gB[1] ^ w1) + __popcll(gB[2] ^ w2) +
              __popcll(gB[3] ^ w3) + __popcll(gB[4] ^ w4) + __popcll(gB[5] ^ w5);
    opA[i * (HH * WW)] = bbv[i] - 2.0f * (float)mmA;
    opB[i * (HH * WW)] = bbv[i] - 2.0f * (float)mmB;
  }
}

extern "C" void kernel_launch(void* const* d_in, const int* in_sizes, int n_in,
                              void* d_out, int out_size, void* d_ws, size_t ws_size,
                              hipStream_t stream) {
  const float* x = (const float*)d_in[0];
  const float* wgt = (const float*)d_in[1];
  const float* bias = (const float*)d_in[2];
  float* out = (float*)d_out;

  uint64_t* wbg = (uint64_t*)d_ws;                                       // 18432 B
  float* bias2t = (float*)((char*)d_ws + 18432);                         // 49152 B
  uint64_t* G = (uint64_t*)((char*)d_ws + 18432 + 49152);                // 3 MB
  const size_t need = 18432 + 49152 + (size_t)BB * HH * WW * 6 * 8;

  cyc_prep<<<IN_CH, 64, 0, stream>>>(wgt, bias, wbg, bias2t);
  if (ws_size >= need) {
    cyc_pack<<<BB * (HH / HR), 768, 0, stream>>>(x, G);
    cyc_gemm<<<2048, 256, 0, stream>>>(G, wbg, bias2t, out);
  } else {
    cyc_main<<<BB * (HH / HR), 768, 0, stream>>>(x, wbg, bias2t, out);
  }
}